// Round 6
// baseline (308.002 us; speedup 1.0000x reference)
//
#include <hip/hip_runtime.h>
#include <hip/hip_bf16.h>
#include <math.h>

#define BATCH 256
#define DM    768
#define REPR  1024
#define FF    3072
#define NBLK  512

typedef __attribute__((ext_vector_type(8))) short bf16x8;
typedef __attribute__((ext_vector_type(4))) float f32x4;

__device__ __forceinline__ unsigned bf16rne(float f){
  union{float f; unsigned u;} x; x.f = f;
  return (x.u + 0x7FFFu + ((x.u >> 16) & 1u)) >> 16;
}
__device__ __forceinline__ unsigned pk2(float lo, float hi){
  return bf16rne(lo) | (bf16rne(hi) << 16);
}

// ---------------------------------------------------------------------------
// grid barrier: arrive on cnt[i], last arriver releases rel[i]; pollers spin
// on rel[i] (separate line from cnt -> polls don't serialize arrivals).
// Device-scope atomics + __threadfence release/acquire handle cross-XCD L2
// non-coherence. Bounded spin: if co-residency assumption ever broke, we fail
// visibly (wrong output) instead of hanging the harness.
// ---------------------------------------------------------------------------
__global__ __launch_bounds__(64)
void zero_bar(unsigned* bar){ if (threadIdx.x < 16) bar[threadIdx.x] = 0; }

__device__ __forceinline__ void gbar(unsigned* cnt, unsigned* rel, int i){
  __syncthreads();                      // all waves' stores drained (vmcnt 0)
  if (threadIdx.x == 0) {
    __threadfence();                    // release: block's writes device-visible
    if (atomicAdd(&cnt[i], 1u) == NBLK - 1u) {
      __threadfence();
      atomicExch(&rel[i], 1u);          // open the gate
    } else {
      unsigned it = 0;
      while (atomicAdd(&rel[i], 0u) == 0u && it < (1u << 20)) {
        __builtin_amdgcn_s_sleep(8); ++it;
      }
    }
    __threadfence();                    // acquire: invalidate stale cache
  }
  __syncthreads();
}

// ---------------------------------------------------------------------------
// 64x64 transpose tile: W[K][N] f32 -> Wt[N][K] bf16 (coalesced both phases).
// ---------------------------------------------------------------------------
__device__ __forceinline__
void tr_tile(const float* __restrict__ src, ushort* __restrict__ dst,
             int K, int N, int rel, int ntk, float (*lds)[65], int tid)
{
  const int k0 = (rel % ntk) * 64, n0 = (rel / ntk) * 64;
  #pragma unroll
  for (int p = 0; p < 4; ++p) {
    const int r = p * 16 + (tid >> 4), c4 = (tid & 15) * 4;
    float4 v = *(const float4*)(src + (size_t)(k0 + r) * N + n0 + c4);
    lds[r][c4] = v.x; lds[r][c4+1] = v.y; lds[r][c4+2] = v.z; lds[r][c4+3] = v.w;
  }
  __syncthreads();
  #pragma unroll
  for (int p = 0; p < 4; ++p) {
    const int nn = p * 16 + (tid >> 4), k4 = (tid & 15) * 4;
    uint2 o = { pk2(lds[k4][nn], lds[k4+1][nn]),
                pk2(lds[k4+2][nn], lds[k4+3][nn]) };
    *(uint2*)(dst + (size_t)(n0 + nn) * K + k0 + k4) = o;
  }
  __syncthreads();                      // lds reused by next grid-stride job
}

// ---------------------------------------------------------------------------
// register-only GEMM job (r4-proven): 32x64 tile, 4 waves 2x2, depth-1
// prefetch. A bf16 [M][lda], Bt bf16 [N][K]. Frag map: in row/col = lane&15,
// k-octet = lane>>4; out col = lane&15, row = (lane>>4)*4 + r.
// EPI 0: raw f32 partial -> outF[z][BATCH][N];  EPI 1: +bias,gelu -> bf16 outH
// ---------------------------------------------------------------------------
template<int NSTEPS, int EPI>
__device__ __forceinline__
void gemm_job(const ushort* __restrict__ Abf, const ushort* __restrict__ Bt,
              const float* __restrict__ bias, float* __restrict__ outF,
              ushort* __restrict__ outH, int N, int K, int lda,
              int bx, int by, int z, int tid)
{
  const int lane = tid & 63, wid = tid >> 6;
  const int wr = wid >> 1, wc = wid & 1;
  const int arow = by * 32 + wr * 16 + (lane & 15);
  const int colb = bx * 64 + wc * 32;
  const int kq = (lane >> 4) * 8;
  const int kb = z * NSTEPS * 32;

  const ushort* ap  = Abf + (size_t)arow * lda + kb + kq;
  const ushort* bp0 = Bt + (size_t)(colb + (lane & 15)) * K + kb + kq;
  const ushort* bp1 = Bt + (size_t)(colb + 16 + (lane & 15)) * K + kb + kq;

  f32x4 acc0 = (f32x4)(0.0f), acc1 = (f32x4)(0.0f);
  union U { uint4 q; bf16x8 v; };
  U a_c, b0_c, b1_c;
  a_c.q  = *(const uint4*)ap;
  b0_c.q = *(const uint4*)bp0;
  b1_c.q = *(const uint4*)bp1;

  #pragma unroll
  for (int t = 0; t < NSTEPS; ++t) {
    U a_n, b0_n, b1_n;
    const bool more = (t + 1) < NSTEPS;
    if (more) {                         // issue next-step loads before MFMA
      a_n.q  = *(const uint4*)(ap  + (t + 1) * 32);
      b0_n.q = *(const uint4*)(bp0 + (t + 1) * 32);
      b1_n.q = *(const uint4*)(bp1 + (t + 1) * 32);
    }
    acc0 = __builtin_amdgcn_mfma_f32_16x16x32_bf16(a_c.v, b0_c.v, acc0, 0, 0, 0);
    acc1 = __builtin_amdgcn_mfma_f32_16x16x32_bf16(a_c.v, b1_c.v, acc1, 0, 0, 0);
    if (more) { a_c = a_n; b0_c = b0_n; b1_c = b1_n; }
  }

  const int crow = by * 32 + wr * 16 + (lane >> 4) * 4;
  #pragma unroll
  for (int nf = 0; nf < 2; ++nf) {
    const int c = colb + nf * 16 + (lane & 15);
    const f32x4 a = nf ? acc1 : acc0;
    #pragma unroll
    for (int r = 0; r < 4; ++r) {
      const int row = crow + r;
      if (EPI == 0) {
        outF[(size_t)z * BATCH * N + (size_t)row * N + c] = a[r];
      } else {
        float v = a[r] + bias[c];
        v = 0.5f * v * (1.0f + erff(v * 0.70710678118654752f));
        outH[(size_t)row * N + c] = (ushort)bf16rne(v);
      }
    }
  }
}

// ---------------------------------------------------------------------------
// fused persistent kernel: 6 phases, 5 grid barriers. Weight transposes are
// overlapped into phases 1-2 to balance BW work against latency-bound MFMA.
// ---------------------------------------------------------------------------
__global__ __launch_bounds__(256, 2)
void fused(const float* __restrict__ Wv2, const float* __restrict__ W1,
           const float* __restrict__ W2, const float* __restrict__ im,
           const float* __restrict__ bv2, const float* __restrict__ b1,
           const float* __restrict__ b2, const float* __restrict__ g,
           const float* __restrict__ be,
           ushort* __restrict__ Wv2t, ushort* __restrict__ W1t,
           ushort* __restrict__ W2t, ushort* __restrict__ imbf,
           ushort* __restrict__ xbf, ushort* __restrict__ tbf,
           float* __restrict__ xf, float* __restrict__ P1,
           float* __restrict__ P3, float* __restrict__ out,
           unsigned* bar)
{
  __shared__ float lds[64][65];
  __shared__ float red[4];
  unsigned* cnt = bar;
  unsigned* rel = bar + 8;
  const int blk = blockIdx.x, tid = threadIdx.x;

  // P0: Wv2 transpose (192 tiles) + im bf16 convert (64 jobs)
  for (int j = blk; j < 256; j += NBLK) {
    if (j < 192) tr_tile(Wv2, Wv2t, REPR, DM, j, 16, lds, tid);
    else {
      const int base = (j - 192) * 4096 + tid * 16;
      float4 v0 = *(const float4*)(im + base);
      float4 v1 = *(const float4*)(im + base + 4);
      float4 v2 = *(const float4*)(im + base + 8);
      float4 v3 = *(const float4*)(im + base + 12);
      uint4 o0 = { pk2(v0.x,v0.y), pk2(v0.z,v0.w), pk2(v1.x,v1.y), pk2(v1.z,v1.w) };
      uint4 o1 = { pk2(v2.x,v2.y), pk2(v2.z,v2.w), pk2(v3.x,v3.y), pk2(v3.z,v3.w) };
      *(uint4*)(imbf + base)     = o0;
      *(uint4*)(imbf + base + 8) = o1;
    }
  }
  gbar(cnt, rel, 0);

  // P1: G1 split-4 (384 jobs: P1[z] = im@Wv2 slices) + W1 transpose (576)
  for (int j = blk; j < 960; j += NBLK) {
    if (j < 384) {
      const int t = j % 96;
      gemm_job<8, 0>(imbf, Wv2t, nullptr, P1, nullptr, DM, REPR, REPR,
                     t % 12, t / 12, j / 96, tid);
    } else tr_tile(W1, W1t, DM, FF, j - 384, 12, lds, tid);
  }
  gbar(cnt, rel, 1);

  // P2: fixup x = sum_z P1 + bv2 -> xf,xbf (192 jobs) + W2 transpose (576)
  for (int j = blk; j < 768; j += NBLK) {
    if (j < 192) {
      const int e = (j * 256 + tid) * 4;
      const int c = e % DM;
      float4 s = *(const float4*)(P1 + e);
      #pragma unroll
      for (int zz = 1; zz < 4; ++zz) {
        float4 v = *(const float4*)(P1 + (size_t)zz * BATCH * DM + e);
        s.x += v.x; s.y += v.y; s.z += v.z; s.w += v.w;
      }
      float4 bb = *(const float4*)(bv2 + c);
      s.x += bb.x; s.y += bb.y; s.z += bb.z; s.w += bb.w;
      *(float4*)(xf + e) = s;
      uint2 o = { pk2(s.x, s.y), pk2(s.z, s.w) };
      *(uint2*)(xbf + e) = o;
    } else tr_tile(W2, W2t, FF, DM, j - 192, 48, lds, tid);
  }
  gbar(cnt, rel, 2);

  // P3: G2 tbf = bf16(gelu(x@W1 + b1))  (384 jobs, M=256 N=3072 K=768)
  for (int j = blk; j < 384; j += NBLK)
    gemm_job<24, 1>(xbf, W1t, b1, nullptr, tbf, FF, DM, DM, j % 48, j / 48, 0, tid);
  gbar(cnt, rel, 3);

  // P4: G3 P3[z] = t@W2 slices (384 jobs, M=256 N=768 K=3072 split-4)
  for (int j = blk; j < 384; j += NBLK) {
    const int t = j % 96;
    gemm_job<24, 0>(tbf, W2t, nullptr, P3, nullptr, DM, FF, FF,
                    t % 12, t / 12, j / 96, tid);
  }
  gbar(cnt, rel, 4);

  // P5: LN rows (256 jobs): y = xf + sum_z P3 + b2 -> LayerNorm -> out
  for (int row = blk; row < BATCH; row += NBLK) {
    const int lane = tid & 63, wave = tid >> 6;
    float v[3];
    #pragma unroll
    for (int i = 0; i < 3; ++i) {
      const int c = tid + i * 256;
      float s = xf[(size_t)row * DM + c] + b2[c];
      #pragma unroll
      for (int zz = 0; zz < 4; ++zz) s += P3[((size_t)zz * BATCH + row) * DM + c];
      v[i] = s;
    }
    float s = v[0] + v[1] + v[2];
    #pragma unroll
    for (int o = 32; o > 0; o >>= 1) s += __shfl_down(s, o);
    if (lane == 0) red[wave] = s;
    __syncthreads();
    const float mu = (red[0] + red[1] + red[2] + red[3]) * (1.0f / 768.0f);
    __syncthreads();
    const float d0 = v[0] - mu, d1 = v[1] - mu, d2 = v[2] - mu;
    float q = d0*d0 + d1*d1 + d2*d2;
    #pragma unroll
    for (int o = 32; o > 0; o >>= 1) q += __shfl_down(q, o);
    if (lane == 0) red[wave] = q;
    __syncthreads();
    const float var = (red[0] + red[1] + red[2] + red[3]) * (1.0f / 768.0f);
    const float inv = rsqrtf(var + 1e-12f);
    float* o = out + (size_t)row * DM;
    o[tid      ] = d0 * inv * g[tid      ] + be[tid      ];
    o[tid + 256] = d1 * inv * g[tid + 256] + be[tid + 256];
    o[tid + 512] = d2 * inv * g[tid + 512] + be[tid + 512];
  }
}

// ---------------------------------------------------------------------------
// 2 launches: zero barrier counters, then the persistent fused kernel.
// ws usage ~20.6 MB (ws ~346 MB per fill counters).
// ---------------------------------------------------------------------------
extern "C" void kernel_launch(void* const* d_in, const int* in_sizes, int n_in,
                              void* d_out, int out_size, void* d_ws, size_t ws_size,
                              hipStream_t stream)
{
  const float* im  = (const float*)d_in[0];
  const float* Wv2 = (const float*)d_in[12];
  const float* bv2 = (const float*)d_in[13];
  const float* W1  = (const float*)d_in[14];
  const float* b1  = (const float*)d_in[15];
  const float* W2  = (const float*)d_in[16];
  const float* b2  = (const float*)d_in[17];
  const float* g   = (const float*)d_in[18];
  const float* be  = (const float*)d_in[19];
  float* out = (float*)d_out;

  char* w = (char*)d_ws;
  unsigned* bar  = (unsigned*)(w);           // 16 uints (cnt[8], rel[8])
  ushort* Wv2t = (ushort*)(w + 256);         // 768*1024*2  = 1572864
  ushort* W1t  = (ushort*)(w + 1573120);     // 3072*768*2  = 4718592
  ushort* W2t  = (ushort*)(w + 6291712);     // 768*3072*2  = 4718592
  ushort* imbf = (ushort*)(w + 11010304);    // 256*1024*2  = 524288
  ushort* xbf  = (ushort*)(w + 11534592);    // 256*768*2   = 393216
  ushort* tbf  = (ushort*)(w + 11927808);    // 256*3072*2  = 1572864
  float*  xf   = (float*) (w + 13500672);    // 256*768*4   = 786432
  float*  P1   = (float*) (w + 14287104);    // 4*256*768*4 = 3145728
  float*  P3   = (float*) (w + 17432832);    // 4*256*768*4 = 3145728 -> 20.6MB

  zero_bar<<<1, 64, 0, stream>>>(bar);
  fused<<<NBLK, 256, 0, stream>>>(Wv2, W1, W2, im, bv2, b1, b2, g, be,
                                  Wv2t, W1t, W2t, imbf, xbf, tbf, xf, P1, P3,
                                  out, bar);
}

// Round 7
// 65.555 us; speedup vs baseline: 4.6984x; 4.6984x over previous
//
#include <hip/hip_runtime.h>
#include <hip/hip_bf16.h>
#include <math.h>

#define BATCH 256
#define DM    768
#define REPR  1024
#define FF    3072

typedef __attribute__((ext_vector_type(8))) short bf16x8;
typedef __attribute__((ext_vector_type(4))) float f32x4;

__device__ __forceinline__ unsigned bf16rne(float f){
  union{float f; unsigned u;} x; x.f = f;
  return (x.u + 0x7FFFu + ((x.u >> 16) & 1u)) >> 16;
}
__device__ __forceinline__ unsigned pk2(float lo, float hi){
  return bf16rne(lo) | (bf16rne(hi) << 16);
}

// ---------------------------------------------------------------------------
// prep: transpose+convert W[K][N] f32 -> Wt[N][K] bf16, 64x64 LDS tiles.
// blocks: [0,192) Wv2, [192,768) W1, [768,1344) W2.
// ---------------------------------------------------------------------------
__global__ __launch_bounds__(256)
void prep(const float* __restrict__ Wv2, const float* __restrict__ W1,
          const float* __restrict__ W2,
          ushort* __restrict__ Wv2t, ushort* __restrict__ W1t,
          ushort* __restrict__ W2t)
{
  const int b = blockIdx.x, tid = threadIdx.x;
  const float* src; ushort* dst; int K, N, rel;
  if (b < 192)      { src = Wv2; dst = Wv2t; K = REPR; N = DM; rel = b; }
  else if (b < 768) { src = W1;  dst = W1t;  K = DM;   N = FF; rel = b - 192; }
  else              { src = W2;  dst = W2t;  K = FF;   N = DM; rel = b - 768; }
  const int ntk = K >> 6;
  const int k0 = (rel % ntk) * 64, n0 = (rel / ntk) * 64;

  __shared__ float lds[64][65];          // +1 pad: column reads 2-way (free)
  #pragma unroll
  for (int p = 0; p < 4; ++p) {          // load 64k x 64n f32, coalesced
    const int r = p * 16 + (tid >> 4), c4 = (tid & 15) * 4;
    float4 v = *(const float4*)(src + (size_t)(k0 + r) * N + n0 + c4);
    lds[r][c4] = v.x; lds[r][c4+1] = v.y; lds[r][c4+2] = v.z; lds[r][c4+3] = v.w;
  }
  __syncthreads();
  #pragma unroll
  for (int p = 0; p < 4; ++p) {          // store transposed bf16, coalesced
    const int nn = p * 16 + (tid >> 4), k4 = (tid & 15) * 4;
    uint2 o = { pk2(lds[k4][nn], lds[k4+1][nn]),
                pk2(lds[k4+2][nn], lds[k4+3][nn]) };
    *(uint2*)(dst + (size_t)(n0 + nn) * K + k0 + k4) = o;
  }
}

// ---------------------------------------------------------------------------
// gemm_rr: register-only GEMM, no LDS/barriers. Block tile 32x32 (4 waves
// 2x2, wave = 16x16, ONE mfma per K-step -> 2x the waves of the r4 32x64
// config for latency hiding). Depth-1 prefetch, runtime nsteps (r4-proven
// schedule). Bt bf16 [N][K] pre-transposed.
// A operand: AF32=1 -> f32 source, packed to bf16 in-register (G1: im).
//            AF32=0 -> bf16 source (xbf / tbf).
// Frag map (r3/r4-verified): in row/col = lane&15, k-octet = lane>>4;
//                            out col = lane&15, row = (lane>>4)*4 + r.
// EPI 0: raw f32 partial -> outF[z][BATCH][N]
// EPI 1: +bias, exact gelu -> bf16 outH
// EPI 2: +bias -> f32 outF AND bf16 outH   (G1: produces xf + xbf)
// ---------------------------------------------------------------------------
template<int EPI, bool AF32>
__global__ __launch_bounds__(256)
void gemm_rr(const void* __restrict__ Aptr, const ushort* __restrict__ Bt,
             const float* __restrict__ bias, float* __restrict__ outF,
             ushort* __restrict__ outH, int N, int K, int lda, int nsteps)
{
  const int gx = gridDim.x, gy = gridDim.y;
  const int nwg = gx * gy;
  int id = blockIdx.y * gx + blockIdx.x;
  if ((nwg & 7) == 0) id = (id & 7) * (nwg >> 3) + (id >> 3);  // XCD swizzle
  const int bx = id / gy, by = id % gy;

  const int lane = threadIdx.x & 63, wid = threadIdx.x >> 6;
  const int wr = wid >> 1, wc = wid & 1;
  const int arow = by * 32 + wr * 16 + (lane & 15);
  const int col  = bx * 32 + wc * 16 + (lane & 15);
  const int kq = (lane >> 4) * 8;
  const int kb = blockIdx.z * nsteps * 32;

  const float*  apf = (const float*)Aptr  + (size_t)arow * lda + kb + kq;
  const ushort* aph = (const ushort*)Aptr + (size_t)arow * lda + kb + kq;
  const ushort* bp  = Bt + (size_t)col * K + kb + kq;

  f32x4 acc = (f32x4)(0.0f);
  union U { uint4 q; bf16x8 v; };
  U a_c, b_c;
  float4 af0, af1;
  if (AF32) { af0 = *(const float4*)apf; af1 = *(const float4*)(apf + 4); }
  else      { a_c.q = *(const uint4*)aph; }
  b_c.q = *(const uint4*)bp;

  for (int t = 0; t < nsteps; ++t) {
    U a_n, b_n;
    float4 af0n, af1n;
    const bool more = (t + 1) < nsteps;
    if (more) {                          // issue next-step loads before MFMA
      if (AF32) {
        const float* a2 = apf + (t + 1) * 32;
        af0n = *(const float4*)a2; af1n = *(const float4*)(a2 + 4);
      } else {
        a_n.q = *(const uint4*)(aph + (t + 1) * 32);
      }
      b_n.q = *(const uint4*)(bp + (t + 1) * 32);
    }
    if (AF32) {                          // pack current A to bf16 in-register
      a_c.q.x = pk2(af0.x, af0.y); a_c.q.y = pk2(af0.z, af0.w);
      a_c.q.z = pk2(af1.x, af1.y); a_c.q.w = pk2(af1.z, af1.w);
    }
    acc = __builtin_amdgcn_mfma_f32_16x16x32_bf16(a_c.v, b_c.v, acc, 0, 0, 0);
    if (more) {
      if (AF32) { af0 = af0n; af1 = af1n; } else { a_c = a_n; }
      b_c = b_n;
    }
  }

  const int crow = by * 32 + wr * 16 + (lane >> 4) * 4;
  #pragma unroll
  for (int r = 0; r < 4; ++r) {
    const int row = crow + r;
    if (EPI == 0) {
      outF[(size_t)blockIdx.z * BATCH * N + (size_t)row * N + col] = acc[r];
    } else if (EPI == 1) {
      float v = acc[r] + bias[col];
      v = 0.5f * v * (1.0f + erff(v * 0.70710678118654752f));
      outH[(size_t)row * N + col] = (ushort)bf16rne(v);
    } else {
      float v = acc[r] + bias[col];
      outF[(size_t)row * N + col] = v;
      outH[(size_t)row * N + col] = (ushort)bf16rne(v);
    }
  }
}

// ---------------------------------------------------------------------------
// ln_final: y = xf + sum_{z<4} P3[z] + b2, then LayerNorm -> out. 1 block/row.
// ---------------------------------------------------------------------------
__global__ __launch_bounds__(256)
void ln_final(const float* __restrict__ P3, const float* __restrict__ xf,
              const float* __restrict__ b2, const float* __restrict__ g,
              const float* __restrict__ be, float* __restrict__ out)
{
  const int row = blockIdx.x, tid = threadIdx.x;
  const int lane = tid & 63, wave = tid >> 6;

  float v[3];
  #pragma unroll
  for (int i = 0; i < 3; ++i) {
    const int c = tid + i * 256;
    float s = xf[(size_t)row * DM + c] + b2[c];
    #pragma unroll
    for (int z = 0; z < 4; ++z) s += P3[((size_t)z * BATCH + row) * DM + c];
    v[i] = s;
  }

  __shared__ float red[4];
  float s = v[0] + v[1] + v[2];
  #pragma unroll
  for (int o = 32; o > 0; o >>= 1) s += __shfl_down(s, o);
  if (lane == 0) red[wave] = s;
  __syncthreads();
  const float mu = (red[0] + red[1] + red[2] + red[3]) * (1.0f / 768.0f);
  __syncthreads();
  const float d0 = v[0] - mu, d1 = v[1] - mu, d2 = v[2] - mu;
  float q = d0*d0 + d1*d1 + d2*d2;
  #pragma unroll
  for (int o = 32; o > 0; o >>= 1) q += __shfl_down(q, o);
  if (lane == 0) red[wave] = q;
  __syncthreads();
  const float var = (red[0] + red[1] + red[2] + red[3]) * (1.0f / 768.0f);
  const float inv = rsqrtf(var + 1e-12f);

  float* o = out + (size_t)row * DM;
  o[tid      ] = d0 * inv * g[tid      ] + be[tid      ];
  o[tid + 256] = d1 * inv * g[tid + 256] + be[tid + 256];
  o[tid + 512] = d2 * inv * g[tid + 512] + be[tid + 512];
}

// ---------------------------------------------------------------------------
// 5 kernels: prep -> G1 (unsplit, A=im f32, writes xf+xbf) -> G2 -> G3
// (split-4) -> LN. ws usage ~16.9 MB.
// ---------------------------------------------------------------------------
extern "C" void kernel_launch(void* const* d_in, const int* in_sizes, int n_in,
                              void* d_out, int out_size, void* d_ws, size_t ws_size,
                              hipStream_t stream)
{
  const float* im  = (const float*)d_in[0];
  const float* Wv2 = (const float*)d_in[12];
  const float* bv2 = (const float*)d_in[13];
  const float* W1  = (const float*)d_in[14];
  const float* b1  = (const float*)d_in[15];
  const float* W2  = (const float*)d_in[16];
  const float* b2  = (const float*)d_in[17];
  const float* g   = (const float*)d_in[18];
  const float* be  = (const float*)d_in[19];
  float* out = (float*)d_out;

  char* w = (char*)d_ws;
  ushort* Wv2t = (ushort*)(w);               // 768*1024*2  = 1572864
  ushort* W1t  = (ushort*)(w + 1572864);     // 3072*768*2  = 4718592
  ushort* W2t  = (ushort*)(w + 6291456);     // 768*3072*2  = 4718592
  ushort* xbf  = (ushort*)(w + 11010048);    // 256*768*2   = 393216
  ushort* tbf  = (ushort*)(w + 11403264);    // 256*3072*2  = 1572864
  float*  xf   = (float*) (w + 12976128);    // 256*768*4   = 786432
  float*  P3   = (float*) (w + 13762560);    // 4*256*768*4 = 3145728 -> 16.9MB

  // K1: transpose/convert weights
  prep<<<1344, 256, 0, stream>>>(Wv2, W1, W2, Wv2t, W1t, W2t);
  // K2 G1: x = im @ Wv2 + bv2 -> xf (f32) + xbf (bf16)  (M=256,N=768,K=1024)
  gemm_rr<2, true><<<dim3(24, 8, 1), 256, 0, stream>>>(im, Wv2t, bv2, xf, xbf,
                                                       DM, REPR, REPR, 32);
  // K3 G2: tbf = bf16(gelu(x @ W1 + b1))                (M=256,N=3072,K=768)
  gemm_rr<1, false><<<dim3(96, 8, 1), 256, 0, stream>>>(xbf, W1t, b1, nullptr, tbf,
                                                        FF, DM, DM, 24);
  // K4 G3: P3[z] = (t @ W2) K-slices                    (M=256,N=768,K=3072, split-4)
  gemm_rr<0, false><<<dim3(24, 8, 4), 256, 0, stream>>>(tbf, W2t, nullptr, P3, nullptr,
                                                        DM, FF, FF, 24);
  // K5: LN(xf + sum P3 + b2) -> out
  ln_final<<<BATCH, 256, 0, stream>>>(P3, xf, b2, g, be, out);
}

// Round 8
// 54.433 us; speedup vs baseline: 5.6584x; 1.2043x over previous
//
#include <hip/hip_runtime.h>
#include <hip/hip_bf16.h>
#include <math.h>

#define BATCH 256
#define DM    768
#define REPR  1024
#define FF    3072

typedef __attribute__((ext_vector_type(8))) short bf16x8;
typedef __attribute__((ext_vector_type(4))) float f32x4;

__device__ __forceinline__ unsigned bf16rne(float f){
  union{float f; unsigned u;} x; x.f = f;
  return (x.u + 0x7FFFu + ((x.u >> 16) & 1u)) >> 16;
}
__device__ __forceinline__ unsigned pk2(float lo, float hi){
  return bf16rne(lo) | (bf16rne(hi) << 16);
}

// ---------------------------------------------------------------------------
// K1 prep_g1: one kernel, two independent block families.
//  ids [0,384):    G1 split-4 (r4-proven grid): P1[z] = im @ Wv2 K-slices,
//                  B read DIRECTLY from raw f32 Wv2 (8 strided dwords per
//                  frag; Wv2 read exactly once -> no Wv2 transpose needed).
//  ids [384,1536): W1/W2 transpose+convert f32[K][N] -> bf16[N][K], 64x64
//                  LDS tiles (r4-proven).
// Latency-bound G1 waves co-schedule with BW-bound transpose waves.
// ---------------------------------------------------------------------------
__global__ __launch_bounds__(256)
void prep_g1(const float* __restrict__ Wv2, const float* __restrict__ W1,
             const float* __restrict__ W2, const float* __restrict__ im,
             ushort* __restrict__ W1t, ushort* __restrict__ W2t,
             float* __restrict__ P1)
{
  const int id = blockIdx.x, tid = threadIdx.x;

  if (id < 384) {                        // ---- G1 blocks ----
    const int z = id / 96, t2 = id % 96, bx = t2 % 12, by = t2 / 12;
    const int lane = tid & 63, wid = tid >> 6;
    const int wr = wid >> 1, wc = wid & 1;
    const int arow = by * 32 + wr * 16 + (lane & 15);
    const int colb = bx * 64 + wc * 32;
    const int kq8  = (lane >> 4) * 8;
    const int kb   = z * 256;            // 8 K-steps per slice

    const float* apf  = im + (size_t)arow * REPR + kb + kq8;
    const int c0 = colb + (lane & 15), c1 = c0 + 16;
    const float* wrow = Wv2 + (size_t)(kb + kq8) * DM;

    f32x4 acc0 = (f32x4)(0.0f), acc1 = (f32x4)(0.0f);

    float4 a0c = *(const float4*)apf, a1c = *(const float4*)(apf + 4);
    float b0c[8], b1c[8];
    #pragma unroll
    for (int j = 0; j < 8; ++j) {
      b0c[j] = wrow[(size_t)j * DM + c0];
      b1c[j] = wrow[(size_t)j * DM + c1];
    }

    for (int s = 0; s < 8; ++s) {
      float4 a0n, a1n; float b0n[8], b1n[8];
      const bool more = (s + 1) < 8;
      if (more) {                        // depth-1 prefetch (r4 schedule)
        const float* a2 = apf + (s + 1) * 32;
        a0n = *(const float4*)a2; a1n = *(const float4*)(a2 + 4);
        const float* w2r = wrow + (size_t)(s + 1) * 32 * DM;
        #pragma unroll
        for (int j = 0; j < 8; ++j) {
          b0n[j] = w2r[(size_t)j * DM + c0];
          b1n[j] = w2r[(size_t)j * DM + c1];
        }
      }
      union U { unsigned u[4]; bf16x8 v; } afr, bfr0, bfr1;
      afr.u[0] = pk2(a0c.x, a0c.y); afr.u[1] = pk2(a0c.z, a0c.w);
      afr.u[2] = pk2(a1c.x, a1c.y); afr.u[3] = pk2(a1c.z, a1c.w);
      #pragma unroll
      for (int j = 0; j < 4; ++j) {
        bfr0.u[j] = pk2(b0c[2*j], b0c[2*j+1]);
        bfr1.u[j] = pk2(b1c[2*j], b1c[2*j+1]);
      }
      acc0 = __builtin_amdgcn_mfma_f32_16x16x32_bf16(afr.v, bfr0.v, acc0, 0, 0, 0);
      acc1 = __builtin_amdgcn_mfma_f32_16x16x32_bf16(afr.v, bfr1.v, acc1, 0, 0, 0);
      if (more) {
        a0c = a0n; a1c = a1n;
        #pragma unroll
        for (int j = 0; j < 8; ++j) { b0c[j] = b0n[j]; b1c[j] = b1n[j]; }
      }
    }

    const int crow = by * 32 + wr * 16 + (lane >> 4) * 4;
    float* dst = P1 + (size_t)z * BATCH * DM;
    #pragma unroll
    for (int nf = 0; nf < 2; ++nf) {
      const int c = colb + nf * 16 + (lane & 15);
      const f32x4 a = nf ? acc1 : acc0;
      #pragma unroll
      for (int r = 0; r < 4; ++r)
        dst[(size_t)(crow + r) * DM + c] = a[r];
    }
    return;
  }

  // ---- transpose blocks (W1, W2) ----
  const int rel0 = id - 384;
  const float* src; ushort* dst; int K, N, rel;
  if (rel0 < 576) { src = W1; dst = W1t; K = DM; N = FF; rel = rel0; }
  else            { src = W2; dst = W2t; K = FF; N = DM; rel = rel0 - 576; }
  const int ntk = K >> 6;
  const int k0 = (rel % ntk) * 64, n0 = (rel / ntk) * 64;

  __shared__ float lds[64][65];          // +1 pad: column reads 2-way (free)
  #pragma unroll
  for (int p = 0; p < 4; ++p) {
    const int r = p * 16 + (tid >> 4), c4 = (tid & 15) * 4;
    float4 v = *(const float4*)(src + (size_t)(k0 + r) * N + n0 + c4);
    lds[r][c4] = v.x; lds[r][c4+1] = v.y; lds[r][c4+2] = v.z; lds[r][c4+3] = v.w;
  }
  __syncthreads();
  #pragma unroll
  for (int p = 0; p < 4; ++p) {
    const int nn = p * 16 + (tid >> 4), k4 = (tid & 15) * 4;
    uint2 o = { pk2(lds[k4][nn], lds[k4+1][nn]),
                pk2(lds[k4+2][nn], lds[k4+3][nn]) };
    *(uint2*)(dst + (size_t)(n0 + nn) * K + k0 + k4) = o;
  }
}

// ---------------------------------------------------------------------------
// K2 fixup_x: x = sum_z P1[z] + bv2 -> xf (f32) + xbf (bf16). r4-exact.
// ---------------------------------------------------------------------------
__global__ __launch_bounds__(256)
void fixup_x(const float* __restrict__ P1, const float* __restrict__ bv2,
             float* __restrict__ xf, ushort* __restrict__ xbf)
{
  const int e = (blockIdx.x * 256 + threadIdx.x) * 4;
  const int c = e % DM;
  float4 s = *(const float4*)(P1 + e);
  #pragma unroll
  for (int z = 1; z < 4; ++z) {
    float4 v = *(const float4*)(P1 + (size_t)z * BATCH * DM + e);
    s.x += v.x; s.y += v.y; s.z += v.z; s.w += v.w;
  }
  float4 bb = *(const float4*)(bv2 + c);
  s.x += bb.x; s.y += bb.y; s.z += bb.z; s.w += bb.w;
  *(float4*)(xf + e) = s;
  uint2 o = { pk2(s.x, s.y), pk2(s.z, s.w) };
  *(uint2*)(xbf + e) = o;
}

// ---------------------------------------------------------------------------
// gemm_rr: r4-exact register-only GEMM. 32x64 block tile, 4 waves 2x2 (wave
// 16x32, 2 mfma/step, 3 loads/step), depth-1 prefetch, runtime nsteps.
// Frag map (r3/r4-verified): in row/col = lane&15, k-octet = lane>>4;
//                            out col = lane&15, row = (lane>>4)*4 + r.
// EPI 0: raw f32 partial -> outF[z][BATCH][N];  EPI 1: +bias, gelu -> bf16.
// ---------------------------------------------------------------------------
template<int EPI>
__global__ __launch_bounds__(256)
void gemm_rr(const ushort* __restrict__ Abf, const ushort* __restrict__ Bt,
             const float* __restrict__ bias, float* __restrict__ outF,
             ushort* __restrict__ outH, int N, int K, int lda, int kcount)
{
  const int gx = gridDim.x, gy = gridDim.y;
  const int nwg = gx * gy;
  int id = blockIdx.y * gx + blockIdx.x;
  if ((nwg & 7) == 0) id = (id & 7) * (nwg >> 3) + (id >> 3);  // XCD swizzle
  const int bx = id / gy, by = id % gy;

  const int lane = threadIdx.x & 63, wid = threadIdx.x >> 6;
  const int wr = wid >> 1, wc = wid & 1;
  const int arow = by * 32 + wr * 16 + (lane & 15);
  const int colb = bx * 64 + wc * 32;
  const int kq = (lane >> 4) * 8;
  const int kb = blockIdx.z * kcount;

  const ushort* ap  = Abf + (size_t)arow * lda + kb + kq;
  const ushort* bp0 = Bt + (size_t)(colb + (lane & 15)) * K + kb + kq;
  const ushort* bp1 = Bt + (size_t)(colb + 16 + (lane & 15)) * K + kb + kq;

  f32x4 acc0 = (f32x4)(0.0f), acc1 = (f32x4)(0.0f);
  const int nsteps = kcount >> 5;

  union U { uint4 q; bf16x8 v; };
  U a_c, b0_c, b1_c;
  a_c.q  = *(const uint4*)ap;
  b0_c.q = *(const uint4*)bp0;
  b1_c.q = *(const uint4*)bp1;

  for (int t = 0; t < nsteps; ++t) {
    U a_n, b0_n, b1_n;
    const bool more = (t + 1) < nsteps;
    if (more) {                          // issue next-step loads before MFMA
      a_n.q  = *(const uint4*)(ap  + (t + 1) * 32);
      b0_n.q = *(const uint4*)(bp0 + (t + 1) * 32);
      b1_n.q = *(const uint4*)(bp1 + (t + 1) * 32);
    }
    acc0 = __builtin_amdgcn_mfma_f32_16x16x32_bf16(a_c.v, b0_c.v, acc0, 0, 0, 0);
    acc1 = __builtin_amdgcn_mfma_f32_16x16x32_bf16(a_c.v, b1_c.v, acc1, 0, 0, 0);
    if (more) { a_c = a_n; b0_c = b0_n; b1_c = b1_n; }
  }

  const int crow = by * 32 + wr * 16 + (lane >> 4) * 4;
  #pragma unroll
  for (int nf = 0; nf < 2; ++nf) {
    const int c = colb + nf * 16 + (lane & 15);
    const f32x4 a = nf ? acc1 : acc0;
    #pragma unroll
    for (int r = 0; r < 4; ++r) {
      const int row = crow + r;
      if (EPI == 0) {
        outF[(size_t)blockIdx.z * BATCH * N + (size_t)row * N + c] = a[r];
      } else {
        float v = a[r] + bias[c];
        v = 0.5f * v * (1.0f + erff(v * 0.70710678118654752f));
        outH[(size_t)row * N + c] = (ushort)bf16rne(v);
      }
    }
  }
}

// ---------------------------------------------------------------------------
// K5 ln_final: y = xf + sum_{z<8} P3[z] + b2, LayerNorm -> out. r4-exact.
// ---------------------------------------------------------------------------
__global__ __launch_bounds__(256)
void ln_final(const float* __restrict__ P3, const float* __restrict__ xf,
              const float* __restrict__ b2, const float* __restrict__ g,
              const float* __restrict__ be, float* __restrict__ out)
{
  const int row = blockIdx.x, tid = threadIdx.x;
  const int lane = tid & 63, wave = tid >> 6;

  float v[3];
  #pragma unroll
  for (int i = 0; i < 3; ++i) {
    const int c = tid + i * 256;
    float s = xf[(size_t)row * DM + c] + b2[c];
    #pragma unroll
    for (int z = 0; z < 8; ++z) s += P3[((size_t)z * BATCH + row) * DM + c];
    v[i] = s;
  }

  __shared__ float red[4];
  float s = v[0] + v[1] + v[2];
  #pragma unroll
  for (int o = 32; o > 0; o >>= 1) s += __shfl_down(s, o);
  if (lane == 0) red[wave] = s;
  __syncthreads();
  const float mu = (red[0] + red[1] + red[2] + red[3]) * (1.0f / 768.0f);
  __syncthreads();
  const float d0 = v[0] - mu, d1 = v[1] - mu, d2 = v[2] - mu;
  float q = d0*d0 + d1*d1 + d2*d2;
  #pragma unroll
  for (int o = 32; o > 0; o >>= 1) q += __shfl_down(q, o);
  if (lane == 0) red[wave] = q;
  __syncthreads();
  const float var = (red[0] + red[1] + red[2] + red[3]) * (1.0f / 768.0f);
  const float inv = rsqrtf(var + 1e-12f);

  float* o = out + (size_t)row * DM;
  o[tid      ] = d0 * inv * g[tid      ] + be[tid      ];
  o[tid + 256] = d1 * inv * g[tid + 256] + be[tid + 256];
  o[tid + 512] = d2 * inv * g[tid + 512] + be[tid + 512];
}

// ---------------------------------------------------------------------------
// 5 kernels: [prep(W1,W2) + G1-direct split-4] -> fixup_x -> G2 -> G3
// (split-8) -> LN. All GEMM grids identical to the 58.5 µs round-4 config.
// ws usage ~21.6 MB.
// ---------------------------------------------------------------------------
extern "C" void kernel_launch(void* const* d_in, const int* in_sizes, int n_in,
                              void* d_out, int out_size, void* d_ws, size_t ws_size,
                              hipStream_t stream)
{
  const float* im  = (const float*)d_in[0];
  const float* Wv2 = (const float*)d_in[12];
  const float* bv2 = (const float*)d_in[13];
  const float* W1  = (const float*)d_in[14];
  const float* b1  = (const float*)d_in[15];
  const float* W2  = (const float*)d_in[16];
  const float* b2  = (const float*)d_in[17];
  const float* g   = (const float*)d_in[18];
  const float* be  = (const float*)d_in[19];
  float* out = (float*)d_out;

  char* w = (char*)d_ws;
  ushort* W1t = (ushort*)(w);                // 3072*768*2  = 4718592
  ushort* W2t = (ushort*)(w + 4718592);      // 768*3072*2  = 4718592
  ushort* xbf = (ushort*)(w + 9437184);      // 256*768*2   = 393216
  ushort* tbf = (ushort*)(w + 9830400);      // 256*3072*2  = 1572864
  float*  xf  = (float*) (w + 11403264);     // 256*768*4   = 786432
  float*  P1  = (float*) (w + 12189696);     // 4*256*768*4 = 3145728
  float*  P3  = (float*) (w + 15335424);     // 8*256*768*4 = 6291456 -> 21.6MB

  // K1: W1/W2 transpose + G1 (P1[z] = im @ Wv2 slices, direct f32 B)
  prep_g1<<<1536, 256, 0, stream>>>(Wv2, W1, W2, im, W1t, W2t, P1);
  // K2: x = sum P1 + bv2 -> xf, xbf
  fixup_x<<<192, 256, 0, stream>>>(P1, bv2, xf, xbf);
  // K3 G2: tbf = bf16(gelu(x @ W1 + b1))   (M=256,N=3072,K=768)
  gemm_rr<1><<<dim3(48, 8, 1), 256, 0, stream>>>(xbf, W1t, b1, nullptr, tbf,
                                                 FF, DM, DM, 768);
  // K4 G3: P3[z] = (t @ W2) K-slices       (M=256,N=768,K=3072, split-8)
  gemm_rr<0><<<dim3(12, 8, 8), 256, 0, stream>>>(tbf, W2t, nullptr, P3, nullptr,
                                                 DM, FF, FF, 384);
  // K5: LN(xf + sum P3 + b2) -> out
  ln_final<<<BATCH, 256, 0, stream>>>(P3, xf, b2, g, be, out);
}